// Round 3
// baseline (124.376 us; speedup 1.0000x reference)
//
#include <hip/hip_runtime.h>
#include <math.h>

#define EPSF 1e-6f

typedef __attribute__((ext_vector_type(8))) short bf16x8;   // 8 bf16 = 4 VGPR (MFMA A/B frag)
typedef __attribute__((ext_vector_type(4))) float f32x4;    // MFMA C/D frag
typedef __attribute__((ext_vector_type(4))) unsigned short u16x4;
typedef __attribute__((ext_vector_type(8))) unsigned short u16x8;

constexpr int TT = 256, MT = 2000, NP = 7200;

static __device__ __forceinline__ unsigned short f2bf(float f) {
    unsigned int u = __float_as_uint(f);
    u += 0x7FFFu + ((u >> 16) & 1u);
    return (unsigned short)(u >> 16);
}
static __device__ __forceinline__ float frcp(float x) { return __builtin_amdgcn_rcpf(x); }

// Async global->LDS, 16B per lane. LDS dest is wave-uniform base (HW adds lane*16).
static __device__ __forceinline__ void gload_lds16(const unsigned short* g, unsigned short* l) {
    __builtin_amdgcn_global_load_lds(
        (const __attribute__((address_space(1))) unsigned int*)(g),
        (__attribute__((address_space(3))) unsigned int*)(l),
        16, 0, 0);
}

// ---------------- Kernel 1: fused prep (unchanged) ----------------
__global__ __launch_bounds__(256) void prep_kernel(const float* __restrict__ logits,
                                                   const float* __restrict__ lab,
                                                   unsigned short* __restrict__ probs,
                                                   unsigned short* __restrict__ nlab) {
    int b = blockIdx.x;
    if (b < 900) {
        int i = (b * 256 + threadIdx.x) * 8;
        float4 x0 = *reinterpret_cast<const float4*>(logits + i);
        float4 x1 = *reinterpret_cast<const float4*>(logits + i + 4);
        float v[8] = {x0.x, x0.y, x0.z, x0.w, x1.x, x1.y, x1.z, x1.w};
        u16x8 o;
#pragma unroll
        for (int j = 0; j < 8; ++j) {
            float s = frcp(1.0f + __expf(-v[j]));
            s = fminf(fmaxf(s, EPSF), 1.0f - EPSF);
            o[j] = f2bf(s);
        }
        *reinterpret_cast<u16x8*>(probs + i) = o;
    } else {
        int wave = threadIdx.x >> 6;
        int lane = threadIdx.x & 63;
        int m = (b - 900) * 4 + wave;               // [0,2000)
        float4 v = reinterpret_cast<const float4*>(lab)[m * (TT / 4) + lane];
        float s = v.x + v.y + v.z + v.w;
#pragma unroll
        for (int off = 32; off > 0; off >>= 1) s += __shfl_down(s, off);
        float inv = frcp(__shfl(s, 0) + EPSF);
        u16x4 o;
        o[0] = f2bf(v.x * inv); o[1] = f2bf(v.y * inv);
        o[2] = f2bf(v.z * inv); o[3] = f2bf(v.w * inv);
        *reinterpret_cast<u16x4*>(nlab + m * TT + lane * 4) = o;
    }
}

// ---------------- Kernel 2: A-in-LDS / B-in-registers, single barrier ----------------
// R2 postmortem: 64KB LDS -> 2 blocks/CU -> latency-bound (Occupancy 16.5%,
// MfmaUtil 6%). Fix: only A is LDS-staged (32KB, gl_lds + both-sides swizzle);
// all 16 B fragments are loaded straight to registers UPFRONT (independent,
// in-flight during the A-stage drain -- unlike R1's serial per-kk loads).
// 32KB LDS + ~110 VGPR -> 4 blocks/CU, still exactly ONE barrier, no ds_write.
constexpr int NTX = 113, NTY = 32;                  // 3616 tiles, 64x64 each

__global__ __launch_bounds__(256, 4) void cost_mfma_kernel(
    const unsigned short* __restrict__ A,   // probs bf16 [NP][TT]
    const unsigned short* __restrict__ B,   // nlab  bf16 [MT][TT]
    const float* __restrict__ pbox,         // [NP][4] cxcywh
    const float* __restrict__ tbox,         // [MT][4] cxcywh
    float* __restrict__ out)                // [NP][MT] fp32
{
    __shared__ __align__(16) unsigned short As[64 * 256];   // 32 KB, linear dest

    // XCD slab swizzle: XCD c gets contiguous l-range -> A-slab + all-B in its L2.
    int n = blockIdx.x;
    int l = (n & 7) * 452 + (n >> 3);
    const int n0 = (l >> 5) * 64;
    const int m0 = (l & 31) * 64;

    const int tid = threadIdx.x;
    const int lane = tid & 63, wave = tid >> 6;
    const int wr = wave & 1, wc = wave >> 1;        // wave's 32x32 quadrant
    const int fr = lane & 15, quad = lane >> 4;     // fragment row / k-quad

    // ---- B fragments: 16 independent 16B global loads, all issued upfront ----
    const unsigned short* bp[2];
#pragma unroll
    for (int t = 0; t < 2; ++t) {
        int gb = m0 + wc * 32 + t * 16 + fr; if (gb > MT - 1) gb = MT - 1;
        bp[t] = B + gb * TT + quad * 8;
    }
    bf16x8 bg[2][8];
#pragma unroll
    for (int kk = 0; kk < 8; ++kk)
#pragma unroll
        for (int t = 0; t < 2; ++t)
            bg[t][kk] = *reinterpret_cast<const bf16x8*>(bp[t] + kk * 32);

    // ---- A: full K=256 via global_load_lds; source col pre-swizzled so the
    //      linear LDS write realizes the ((row&7)<<4)-XOR layout (rule #21) ----
    {
        const int lro = lane >> 5;                  // 0/1: row within the 1KB issue
        const int lch = lane & 31;                  // 16B chunk within the 512B row
#pragma unroll
        for (int i = 0; i < 8; ++i) {
            int row = wave * 16 + i * 2 + lro;
            int cs = (lch * 16) ^ ((row & 7) << 4); // swizzled byte column
            int gn = n0 + row; gn = gn > NP - 1 ? NP - 1 : gn;
            gload_lds16(A + gn * TT + (cs >> 1), &As[wave * 4096 + i * 512]);
        }
    }
    __syncthreads();   // vmcnt(0) drain (covers B-reg loads too) + the ONLY barrier

    // ---- 32 MFMAs over K=256: A from swizzled LDS, B from registers ----
    const char* aB[2];
    const int xs = (fr & 7) << 4;                   // read-row & 7 == fr & 7
#pragma unroll
    for (int t = 0; t < 2; ++t)
        aB[t] = reinterpret_cast<const char*>(As) + (wr * 32 + t * 16 + fr) * 512;

    f32x4 acc[2][2] = {};
#pragma unroll
    for (int kk = 0; kk < 8; ++kk) {
        int cb = (kk * 64 + quad * 16) ^ xs;        // swizzled byte column
        bf16x8 af[2];
#pragma unroll
        for (int t = 0; t < 2; ++t)
            af[t] = *reinterpret_cast<const bf16x8*>(aB[t] + cb);
#pragma unroll
        for (int ti = 0; ti < 2; ++ti)
#pragma unroll
            for (int tj = 0; tj < 2; ++tj)
                acc[ti][tj] = __builtin_amdgcn_mfma_f32_16x16x32_bf16(
                    af[ti], bg[tj][kk], acc[ti][tj], 0, 0, 0);
    }

    // -------- epilogue: box costs (loads inline; L1-resident, not critical) ----
    float bcx[2], bcy[2], bww[2], bhh[2], bx1[2], by1[2], bx2[2], by2[2], areaB[2];
    int mj[2]; bool mv[2];
#pragma unroll
    for (int tj = 0; tj < 2; ++tj) {
        int gm = m0 + wc * 32 + tj * 16 + fr;
        mv[tj] = gm < MT; mj[tj] = gm;
        int g = mv[tj] ? gm : MT - 1;
        float4 b = *reinterpret_cast<const float4*>(&tbox[g * 4]);
        bcx[tj] = b.x; bcy[tj] = b.y; bww[tj] = b.z; bhh[tj] = b.w;
        bx1[tj] = b.x - 0.5f * b.z; by1[tj] = b.y - 0.5f * b.w;
        bx2[tj] = b.x + 0.5f * b.z; by2[tj] = b.y + 0.5f * b.w;
        areaB[tj] = (bx2[tj] - bx1[tj]) * (by2[tj] - by1[tj]);
    }

#pragma unroll
    for (int ti = 0; ti < 2; ++ti) {
#pragma unroll
        for (int r = 0; r < 4; ++r) {
            int p = n0 + wr * 32 + ti * 16 + quad * 4 + r;   // C/D: row = quad*4 + reg
            if (p >= NP) continue;
            float4 pb4 = *reinterpret_cast<const float4*>(&pbox[p * 4]);
            float ax1 = pb4.x - 0.5f * pb4.z, ay1 = pb4.y - 0.5f * pb4.w;
            float ax2 = pb4.x + 0.5f * pb4.z, ay2 = pb4.y + 0.5f * pb4.w;
            float areaA = (ax2 - ax1) * (ay2 - ay1);
#pragma unroll
            for (int tj = 0; tj < 2; ++tj) {
                if (!mv[tj]) continue;
                float l1 = fabsf(pb4.x - bcx[tj]) + fabsf(pb4.y - bcy[tj]) +
                           fabsf(pb4.z - bww[tj]) + fabsf(pb4.w - bhh[tj]);
                float ltx = fmaxf(ax1, bx1[tj]), lty = fmaxf(ay1, by1[tj]);
                float rbx = fminf(ax2, bx2[tj]), rby = fminf(ay2, by2[tj]);
                float iw = fmaxf(rbx - ltx, 0.0f), ih = fmaxf(rby - lty, 0.0f);
                float inter = iw * ih;
                float uni = areaA + areaB[tj] - inter;
                float iou = inter * frcp(uni + EPSF);
                float ex1 = fminf(ax1, bx1[tj]), ey1 = fminf(ay1, by1[tj]);
                float ex2 = fmaxf(ax2, bx2[tj]), ey2 = fmaxf(ay2, by2[tj]);
                float ew = fmaxf(ex2 - ex1, 0.0f), eh = fmaxf(ey2 - ey1, 0.0f);
                float areaE = ew * eh;
                float giou = iou - (areaE - uni) * frcp(areaE + EPSF);
                float res = 5.0f * l1 - acc[ti][tj][r] - 2.0f * fmaxf(giou, -1.0f);
                out[p * MT + mj[tj]] = res;
            }
        }
    }
}

extern "C" void kernel_launch(void* const* d_in, const int* in_sizes, int n_in,
                              void* d_out, int out_size, void* d_ws, size_t ws_size,
                              hipStream_t stream) {
    const float* pred_logits = (const float*)d_in[0];  // [8,900,256]
    const float* pred_boxes  = (const float*)d_in[1];  // [8,900,4]
    const float* tgt_boxes   = (const float*)d_in[2];  // [2000,4]
    const float* tgt_labels  = (const float*)d_in[3];  // [2000,256]
    float* out = (float*)d_out;                        // [7200,2000]

    unsigned short* probs = (unsigned short*)d_ws;     // 7200*256 bf16 (3.7 MB)
    unsigned short* nlab  = probs + NP * TT;           // 2000*256 bf16 (1.0 MB)

    prep_kernel<<<900 + 500, 256, 0, stream>>>(pred_logits, tgt_labels, probs, nlab);

    cost_mfma_kernel<<<NTX * NTY, 256, 0, stream>>>(probs, nlab, pred_boxes, tgt_boxes, out);
}

// Round 4
// 111.471 us; speedup vs baseline: 1.1158x; 1.1158x over previous
//
#include <hip/hip_runtime.h>
#include <math.h>

#define EPSF 1e-6f

typedef __attribute__((ext_vector_type(8))) short bf16x8;   // 8 bf16 = 4 VGPR (MFMA A/B frag)
typedef __attribute__((ext_vector_type(4))) float f32x4;    // MFMA C/D frag
typedef __attribute__((ext_vector_type(4))) unsigned short u16x4;
typedef __attribute__((ext_vector_type(8))) unsigned short u16x8;

constexpr int TT = 256, MT = 2000, NP = 7200;

static __device__ __forceinline__ unsigned short f2bf(float f) {
    unsigned int u = __float_as_uint(f);
    u += 0x7FFFu + ((u >> 16) & 1u);
    return (unsigned short)(u >> 16);
}
static __device__ __forceinline__ float frcp(float x) { return __builtin_amdgcn_rcpf(x); }

// Async global->LDS, 16B per lane. LDS dest is wave-uniform base (HW adds lane*16).
static __device__ __forceinline__ void gload_lds16(const unsigned short* g, unsigned short* l) {
    __builtin_amdgcn_global_load_lds(
        (const __attribute__((address_space(1))) unsigned int*)(g),
        (__attribute__((address_space(3))) unsigned int*)(l),
        16, 0, 0);
}

// ---------------- Kernel 1: fused prep (unchanged) ----------------
__global__ __launch_bounds__(256) void prep_kernel(const float* __restrict__ logits,
                                                   const float* __restrict__ lab,
                                                   unsigned short* __restrict__ probs,
                                                   unsigned short* __restrict__ nlab) {
    int b = blockIdx.x;
    if (b < 900) {
        int i = (b * 256 + threadIdx.x) * 8;
        float4 x0 = *reinterpret_cast<const float4*>(logits + i);
        float4 x1 = *reinterpret_cast<const float4*>(logits + i + 4);
        float v[8] = {x0.x, x0.y, x0.z, x0.w, x1.x, x1.y, x1.z, x1.w};
        u16x8 o;
#pragma unroll
        for (int j = 0; j < 8; ++j) {
            float s = frcp(1.0f + __expf(-v[j]));
            s = fminf(fmaxf(s, EPSF), 1.0f - EPSF);
            o[j] = f2bf(s);
        }
        *reinterpret_cast<u16x8*>(probs + i) = o;
    } else {
        int wave = threadIdx.x >> 6;
        int lane = threadIdx.x & 63;
        int m = (b - 900) * 4 + wave;               // [0,2000)
        float4 v = reinterpret_cast<const float4*>(lab)[m * (TT / 4) + lane];
        float s = v.x + v.y + v.z + v.w;
#pragma unroll
        for (int off = 32; off > 0; off >>= 1) s += __shfl_down(s, off);
        float inv = frcp(__shfl(s, 0) + EPSF);
        u16x4 o;
        o[0] = f2bf(v.x * inv); o[1] = f2bf(v.y * inv);
        o[2] = f2bf(v.z * inv); o[3] = f2bf(v.w * inv);
        *reinterpret_cast<u16x4*>(nlab + m * TT + lane * 4) = o;
    }
}

// ------- Kernel 2: 8-wave 64x64, half-K planes, counted-vmcnt two-phase -------
// R3 lesson: B must live in LDS (compiler sinks big reg arrays). R2 lesson:
// occupancy + the full vmcnt(0) drain were the stalls. Here: 512 threads,
// LDS = 4 planes [64][128]e (A0,A1,B0,B1; 64 KB). Each wave issues its 8
// gl_lds (chunk0's 4 first, then chunk1's 4), then waits vmcnt(4) -> barrier
// -> computes chunk0 WHILE chunk1 streams -> vmcnt(0) -> barrier -> chunk1.
// Never drains mid-flight (T4). Both-sides XOR swizzle, rule #21, on each
// 256B plane-row: byte ^= ((row&7)<<4). Epilogue loads issued only after the
// last hand-counted wait so they can't corrupt the vmcnt window (m152).
constexpr int NTX = 113, NTY = 32;                  // 3616 tiles, 64x64 each

__global__ __launch_bounds__(512, 4) void cost_mfma_kernel(
    const unsigned short* __restrict__ A,   // probs bf16 [NP][TT]
    const unsigned short* __restrict__ B,   // nlab  bf16 [MT][TT]
    const float* __restrict__ pbox,         // [NP][4] cxcywh
    const float* __restrict__ tbox,         // [MT][4] cxcywh
    float* __restrict__ out)                // [NP][MT] fp32
{
    __shared__ __align__(16) unsigned short S[4][64 * 128];  // A0,A1,B0,B1 planes

    // XCD slab swizzle: XCD c gets contiguous l-range -> A-slab + all-B in its L2.
    int n = blockIdx.x;
    int l = (n & 7) * 452 + (n >> 3);
    const int n0 = (l >> 5) * 64;
    const int m0 = (l & 31) * 64;

    const int tid = threadIdx.x;
    const int lane = tid & 63, wave = tid >> 6;     // 8 waves
    const int wr = wave & 1, wc = wave >> 1;        // wave tile: 32 rows x 16 cols
    const int fr = lane & 15, quad = lane >> 4;     // fragment row / k-quad

    // ---- stage: wave w covers rows [w*8, w*8+8) of every plane ----
    // One gl_lds = 64 lanes x 16B = 1KB = 4 plane-rows (256B each).
    // lane -> (row_off = lane>>4, ch = lane&15). Source column pre-swizzled
    // with ((row&7)<<4) so the linear LDS write realizes the XOR layout.
    {
        const int row_off = lane >> 4;
        const int ch = lane & 15;
#pragma unroll
        for (int c = 0; c < 2; ++c) {               // chunk0 planes first, then chunk1
#pragma unroll
            for (int i = 0; i < 2; ++i) {
                int r = wave * 8 + i * 4 + row_off;
                int cs = (ch * 16) ^ (((i * 4 + row_off) & 7) << 4);  // r&7 indep of wave
                int gn = n0 + r; gn = gn > NP - 1 ? NP - 1 : gn;
                gload_lds16(A + gn * TT + c * 128 + (cs >> 1),
                            &S[c][(wave * 8 + i * 4) * 128]);
            }
#pragma unroll
            for (int i = 0; i < 2; ++i) {
                int r = wave * 8 + i * 4 + row_off;
                int cs = (ch * 16) ^ (((i * 4 + row_off) & 7) << 4);
                int gm = m0 + r; gm = gm > MT - 1 ? MT - 1 : gm;
                gload_lds16(B + gm * TT + c * 128 + (cs >> 1),
                            &S[2 + c][(wave * 8 + i * 4) * 128]);
            }
        }
    }

    const int xs = (fr & 7) << 4;                   // read-row & 7 == fr & 7
    f32x4 acc[2] = {};

    // ---- phase 0: own chunk-0 loads landed (4 chunk-1 still in flight) ----
    asm volatile("s_waitcnt vmcnt(4)" ::: "memory");
    __builtin_amdgcn_s_barrier();
    __builtin_amdgcn_sched_barrier(0);
#pragma unroll
    for (int c = 0; c < 2; ++c) {
        const char* aB = reinterpret_cast<const char*>(&S[c][0]) + (wr * 32 + fr) * 256;
        const char* bB = reinterpret_cast<const char*>(&S[2 + c][0]) + (wc * 16 + fr) * 256;
        __builtin_amdgcn_s_setprio(1);
#pragma unroll
        for (int kk = 0; kk < 4; ++kk) {
            int cb = (kk * 64 + quad * 16) ^ xs;    // swizzled byte column
            bf16x8 af0 = *reinterpret_cast<const bf16x8*>(aB + cb);
            bf16x8 af1 = *reinterpret_cast<const bf16x8*>(aB + 16 * 256 + cb);
            bf16x8 bg  = *reinterpret_cast<const bf16x8*>(bB + cb);
            acc[0] = __builtin_amdgcn_mfma_f32_16x16x32_bf16(af0, bg, acc[0], 0, 0, 0);
            acc[1] = __builtin_amdgcn_mfma_f32_16x16x32_bf16(af1, bg, acc[1], 0, 0, 0);
        }
        __builtin_amdgcn_s_setprio(0);
        if (c == 0) {   // ---- phase boundary: chunk-1 data now required ----
            asm volatile("s_waitcnt vmcnt(0)" ::: "memory");
            __builtin_amdgcn_s_barrier();
            __builtin_amdgcn_sched_barrier(0);
        }
    }

    // -------- epilogue: all loads AFTER the counted-vmcnt window --------
    const int mj = m0 + wc * 16 + fr;
    const bool mv = mj < MT;
    {
        int g = mv ? mj : MT - 1;
        float4 b = *reinterpret_cast<const float4*>(&tbox[g * 4]);
        float bcx = b.x, bcy = b.y, bww = b.z, bhh = b.w;
        float bx1 = b.x - 0.5f * b.z, by1 = b.y - 0.5f * b.w;
        float bx2 = b.x + 0.5f * b.z, by2 = b.y + 0.5f * b.w;
        float areaB = (bx2 - bx1) * (by2 - by1);

#pragma unroll
        for (int ti = 0; ti < 2; ++ti) {
#pragma unroll
            for (int r = 0; r < 4; ++r) {
                int p = n0 + wr * 32 + ti * 16 + quad * 4 + r;  // C/D: row = quad*4 + reg
                if (p >= NP || !mv) continue;
                float4 pb4 = *reinterpret_cast<const float4*>(&pbox[p * 4]);
                float ax1 = pb4.x - 0.5f * pb4.z, ay1 = pb4.y - 0.5f * pb4.w;
                float ax2 = pb4.x + 0.5f * pb4.z, ay2 = pb4.y + 0.5f * pb4.w;
                float areaA = (ax2 - ax1) * (ay2 - ay1);
                float l1 = fabsf(pb4.x - bcx) + fabsf(pb4.y - bcy) +
                           fabsf(pb4.z - bww) + fabsf(pb4.w - bhh);
                float ltx = fmaxf(ax1, bx1), lty = fmaxf(ay1, by1);
                float rbx = fminf(ax2, bx2), rby = fminf(ay2, by2);
                float iw = fmaxf(rbx - ltx, 0.0f), ih = fmaxf(rby - lty, 0.0f);
                float inter = iw * ih;
                float uni = areaA + areaB - inter;
                float iou = inter * frcp(uni + EPSF);
                float ex1 = fminf(ax1, bx1), ey1 = fminf(ay1, by1);
                float ex2 = fmaxf(ax2, bx2), ey2 = fmaxf(ay2, by2);
                float ew = fmaxf(ex2 - ex1, 0.0f), eh = fmaxf(ey2 - ey1, 0.0f);
                float areaE = ew * eh;
                float giou = iou - (areaE - uni) * frcp(areaE + EPSF);
                float res = 5.0f * l1 - acc[ti][r] - 2.0f * fmaxf(giou, -1.0f);
                out[p * MT + mj] = res;
            }
        }
    }
}

extern "C" void kernel_launch(void* const* d_in, const int* in_sizes, int n_in,
                              void* d_out, int out_size, void* d_ws, size_t ws_size,
                              hipStream_t stream) {
    const float* pred_logits = (const float*)d_in[0];  // [8,900,256]
    const float* pred_boxes  = (const float*)d_in[1];  // [8,900,4]
    const float* tgt_boxes   = (const float*)d_in[2];  // [2000,4]
    const float* tgt_labels  = (const float*)d_in[3];  // [2000,256]
    float* out = (float*)d_out;                        // [7200,2000]

    unsigned short* probs = (unsigned short*)d_ws;     // 7200*256 bf16 (3.7 MB)
    unsigned short* nlab  = probs + NP * TT;           // 2000*256 bf16 (1.0 MB)

    prep_kernel<<<900 + 500, 256, 0, stream>>>(pred_logits, tgt_labels, probs, nlab);

    cost_mfma_kernel<<<NTX * NTY, 512, 0, stream>>>(probs, nlab, pred_boxes, tgt_boxes, out);
}

// Round 5
// 105.895 us; speedup vs baseline: 1.1745x; 1.0526x over previous
//
#include <hip/hip_runtime.h>
#include <math.h>

#define EPSF 1e-6f

typedef __attribute__((ext_vector_type(8))) short bf16x8;   // 8 bf16 = 4 VGPR (MFMA A/B frag)
typedef __attribute__((ext_vector_type(4))) float f32x4;    // MFMA C/D frag
typedef __attribute__((ext_vector_type(4))) unsigned short u16x4;
typedef __attribute__((ext_vector_type(8))) unsigned short u16x8;

constexpr int TT = 256, MT = 2000, NP = 7200;

static __device__ __forceinline__ unsigned short f2bf(float f) {
    unsigned int u = __float_as_uint(f);
    u += 0x7FFFu + ((u >> 16) & 1u);
    return (unsigned short)(u >> 16);
}
static __device__ __forceinline__ float frcp(float x) { return __builtin_amdgcn_rcpf(x); }

// Async global->LDS, 16B per lane. LDS dest is wave-uniform base (HW adds lane*16).
static __device__ __forceinline__ void gload_lds16(const unsigned short* g, unsigned short* l) {
    __builtin_amdgcn_global_load_lds(
        (const __attribute__((address_space(1))) unsigned int*)(g),
        (__attribute__((address_space(3))) unsigned int*)(l),
        16, 0, 0);
}

// ---------------- Kernel 1: fused prep (unchanged) ----------------
__global__ __launch_bounds__(256) void prep_kernel(const float* __restrict__ logits,
                                                   const float* __restrict__ lab,
                                                   unsigned short* __restrict__ probs,
                                                   unsigned short* __restrict__ nlab) {
    int b = blockIdx.x;
    if (b < 900) {
        int i = (b * 256 + threadIdx.x) * 8;
        float4 x0 = *reinterpret_cast<const float4*>(logits + i);
        float4 x1 = *reinterpret_cast<const float4*>(logits + i + 4);
        float v[8] = {x0.x, x0.y, x0.z, x0.w, x1.x, x1.y, x1.z, x1.w};
        u16x8 o;
#pragma unroll
        for (int j = 0; j < 8; ++j) {
            float s = frcp(1.0f + __expf(-v[j]));
            s = fminf(fmaxf(s, EPSF), 1.0f - EPSF);
            o[j] = f2bf(s);
        }
        *reinterpret_cast<u16x8*>(probs + i) = o;
    } else {
        int wave = threadIdx.x >> 6;
        int lane = threadIdx.x & 63;
        int m = (b - 900) * 4 + wave;               // [0,2000)
        float4 v = reinterpret_cast<const float4*>(lab)[m * (TT / 4) + lane];
        float s = v.x + v.y + v.z + v.w;
#pragma unroll
        for (int off = 32; off > 0; off >>= 1) s += __shfl_down(s, off);
        float inv = frcp(__shfl(s, 0) + EPSF);
        u16x4 o;
        o[0] = f2bf(v.x * inv); o[1] = f2bf(v.y * inv);
        o[2] = f2bf(v.z * inv); o[3] = f2bf(v.w * inv);
        *reinterpret_cast<u16x4*>(nlab + m * TT + lane * 4) = o;
    }
}

// ------ Kernel 2: 256-thread 64x64, K chunked 2x128, 32KB LDS, 5 blocks/CU ------
// Ledger R0-R4: time tracks blocks/CU (R0 4/CU=34us beats R2/R4 2/CU=44-46us),
// not barrier count or vmcnt discipline -- K is too shallow for intra-block
// pipelining; latency hiding must come from INTER-block TLP. So: minimize LDS.
// Single 32KB buffer (A+B, one K-half), 2 chunks with 3 barriers (R0 schedule),
// gl_lds staging (no reg round-trip), both-sides XOR swizzle (rule #21).
// __launch_bounds__(256,5): 5 blocks/CU (LDS 160/32), 20 waves/CU, VGPR<=102.
constexpr int NTX = 113, NTY = 32;                  // 3616 tiles, 64x64 each

__global__ __launch_bounds__(256, 5) void cost_mfma_kernel(
    const unsigned short* __restrict__ A,   // probs bf16 [NP][TT]
    const unsigned short* __restrict__ B,   // nlab  bf16 [MT][TT]
    const float* __restrict__ pbox,         // [NP][4] cxcywh
    const float* __restrict__ tbox,         // [MT][4] cxcywh
    float* __restrict__ out)                // [NP][MT] fp32
{
    __shared__ __align__(16) unsigned short As[64 * 128];   // 16 KB (one K-half)
    __shared__ __align__(16) unsigned short Bs[64 * 128];   // 16 KB

    // XCD slab swizzle: XCD c gets contiguous l-range -> A-slab + all-B in its L2.
    int n = blockIdx.x;
    int l = (n & 7) * 452 + (n >> 3);
    const int n0 = (l >> 5) * 64;
    const int m0 = (l & 31) * 64;

    const int tid = threadIdx.x;
    const int lane = tid & 63, wave = tid >> 6;     // 4 waves
    const int wr = wave & 1, wc = wave >> 1;        // wave's 32x32 quadrant
    const int fr = lane & 15, quad = lane >> 4;     // fragment row / k-quad

    // Staging geometry: wave w covers rows [w*16, w*16+16) of each plane.
    // One gl_lds = 64 lanes x 16B = 1KB = 4 plane-rows (256B each).
    const int row_off = lane >> 4;                  // 0..3: row within the 1KB issue
    const int ch = lane & 15;                       // 16B chunk within the 256B row
    int gnr[4], gmr[4], csr[4];
#pragma unroll
    for (int i = 0; i < 4; ++i) {
        int r = wave * 16 + i * 4 + row_off;
        csr[i] = (ch * 16) ^ ((r & 7) << 4);        // swizzled source byte column
        int gn = n0 + r; gnr[i] = gn > NP - 1 ? NP - 1 : gn;
        int gm = m0 + r; gmr[i] = gm > MT - 1 ? MT - 1 : gm;
    }

    const int xs = (fr & 7) << 4;                   // read-row & 7 == fr & 7
    const char* aB = reinterpret_cast<const char*>(As) + (wr * 32 + fr) * 256;
    const char* bB = reinterpret_cast<const char*>(Bs) + (wc * 32 + fr) * 256;

    f32x4 acc[2][2] = {};
#pragma unroll
    for (int c = 0; c < 2; ++c) {                   // two K-halves of 128
        // ---- stage chunk c (4 A-issues + 4 B-issues per wave) ----
#pragma unroll
        for (int i = 0; i < 4; ++i) {
            gload_lds16(A + gnr[i] * TT + c * 128 + (csr[i] >> 1),
                        &As[(wave * 16 + i * 4) * 128]);
            gload_lds16(B + gmr[i] * TT + c * 128 + (csr[i] >> 1),
                        &Bs[(wave * 16 + i * 4) * 128]);
        }
        __syncthreads();    // vmcnt(0) drain + barrier: chunk ready

        __builtin_amdgcn_s_setprio(1);
#pragma unroll
        for (int kk = 0; kk < 4; ++kk) {
            int cb = (kk * 64 + quad * 16) ^ xs;    // swizzled byte column
            bf16x8 af[2], bg[2];
#pragma unroll
            for (int t = 0; t < 2; ++t) {
                af[t] = *reinterpret_cast<const bf16x8*>(aB + t * 16 * 256 + cb);
                bg[t] = *reinterpret_cast<const bf16x8*>(bB + t * 16 * 256 + cb);
            }
#pragma unroll
            for (int ti = 0; ti < 2; ++ti)
#pragma unroll
                for (int tj = 0; tj < 2; ++tj)
                    acc[ti][tj] = __builtin_amdgcn_mfma_f32_16x16x32_bf16(
                        af[ti], bg[tj], acc[ti][tj], 0, 0, 0);
        }
        __builtin_amdgcn_s_setprio(0);
        if (c == 0) __syncthreads();    // all waves done reading before overwrite
    }

    // -------- epilogue: box costs (loads inline; rows hot in L1/L2) --------
    float bcx[2], bcy[2], bww[2], bhh[2], bx1[2], by1[2], bx2[2], by2[2], areaB[2];
    int mj[2]; bool mv[2];
#pragma unroll
    for (int tj = 0; tj < 2; ++tj) {
        int gm = m0 + wc * 32 + tj * 16 + fr;
        mv[tj] = gm < MT; mj[tj] = gm;
        int g = mv[tj] ? gm : MT - 1;
        float4 b = *reinterpret_cast<const float4*>(&tbox[g * 4]);
        bcx[tj] = b.x; bcy[tj] = b.y; bww[tj] = b.z; bhh[tj] = b.w;
        bx1[tj] = b.x - 0.5f * b.z; by1[tj] = b.y - 0.5f * b.w;
        bx2[tj] = b.x + 0.5f * b.z; by2[tj] = b.y + 0.5f * b.w;
        areaB[tj] = (bx2[tj] - bx1[tj]) * (by2[tj] - by1[tj]);
    }

#pragma unroll
    for (int ti = 0; ti < 2; ++ti) {
#pragma unroll
        for (int r = 0; r < 4; ++r) {
            int p = n0 + wr * 32 + ti * 16 + quad * 4 + r;   // C/D: row = quad*4 + reg
            if (p >= NP) continue;
            float4 pb4 = *reinterpret_cast<const float4*>(&pbox[p * 4]);
            float ax1 = pb4.x - 0.5f * pb4.z, ay1 = pb4.y - 0.5f * pb4.w;
            float ax2 = pb4.x + 0.5f * pb4.z, ay2 = pb4.y + 0.5f * pb4.w;
            float areaA = (ax2 - ax1) * (ay2 - ay1);
#pragma unroll
            for (int tj = 0; tj < 2; ++tj) {
                if (!mv[tj]) continue;
                float l1 = fabsf(pb4.x - bcx[tj]) + fabsf(pb4.y - bcy[tj]) +
                           fabsf(pb4.z - bww[tj]) + fabsf(pb4.w - bhh[tj]);
                float ltx = fmaxf(ax1, bx1[tj]), lty = fmaxf(ay1, by1[tj]);
                float rbx = fminf(ax2, bx2[tj]), rby = fminf(ay2, by2[tj]);
                float iw = fmaxf(rbx - ltx, 0.0f), ih = fmaxf(rby - lty, 0.0f);
                float inter = iw * ih;
                float uni = areaA + areaB[tj] - inter;
                float iou = inter * frcp(uni + EPSF);
                float ex1 = fminf(ax1, bx1[tj]), ey1 = fminf(ay1, by1[tj]);
                float ex2 = fmaxf(ax2, bx2[tj]), ey2 = fmaxf(ay2, by2[tj]);
                float ew = fmaxf(ex2 - ex1, 0.0f), eh = fmaxf(ey2 - ey1, 0.0f);
                float areaE = ew * eh;
                float giou = iou - (areaE - uni) * frcp(areaE + EPSF);
                float res = 5.0f * l1 - acc[ti][tj][r] - 2.0f * fmaxf(giou, -1.0f);
                out[p * MT + mj[tj]] = res;
            }
        }
    }
}

extern "C" void kernel_launch(void* const* d_in, const int* in_sizes, int n_in,
                              void* d_out, int out_size, void* d_ws, size_t ws_size,
                              hipStream_t stream) {
    const float* pred_logits = (const float*)d_in[0];  // [8,900,256]
    const float* pred_boxes  = (const float*)d_in[1];  // [8,900,4]
    const float* tgt_boxes   = (const float*)d_in[2];  // [2000,4]
    const float* tgt_labels  = (const float*)d_in[3];  // [2000,256]
    float* out = (float*)d_out;                        // [7200,2000]

    unsigned short* probs = (unsigned short*)d_ws;     // 7200*256 bf16 (3.7 MB)
    unsigned short* nlab  = probs + NP * TT;           // 2000*256 bf16 (1.0 MB)

    prep_kernel<<<900 + 500, 256, 0, stream>>>(pred_logits, tgt_labels, probs, nlab);

    cost_mfma_kernel<<<NTX * NTY, 256, 0, stream>>>(probs, nlab, pred_boxes, tgt_boxes, out);
}